// Round 11
// baseline (1257.064 us; speedup 1.0000x reference)
//
#include <hip/hip_runtime.h>

#define NN 150000
#define NP 150016   // NN padded to multiple of 128
#define NE 600000
#define NG 8192
#define DD 128
#define FINN 16
#define NL 4
#define NEL 500000
#define BN_EPS 1e-5f
#define NB_SCAN 147  // ceil(NN/1024)

typedef __attribute__((ext_vector_type(8))) short bf16x8;
typedef __attribute__((ext_vector_type(4))) float f32x4;
typedef __attribute__((ext_vector_type(2))) float f32x2;

__device__ inline short bfr(float x) {
    unsigned u = __builtin_bit_cast(unsigned, x);
    unsigned r = u + 0x7fffu + ((u >> 16) & 1u);
    return (short)(r >> 16);
}
__device__ inline float bf2f(short h) {
    return __builtin_bit_cast(float, ((unsigned)(unsigned short)h) << 16);
}

// ---------------- encoder: A[n][d] = x[n][:16] @ encW + encb ----------------
__global__ __launch_bounds__(256) void enc_kernel(const float* __restrict__ x,
                                                  const float* __restrict__ W,
                                                  const float* __restrict__ b,
                                                  float* __restrict__ out) {
    int t = threadIdx.x;
    int c4 = (t & 31) * 4;
    float4 wreg[16];
#pragma unroll
    for (int k = 0; k < 16; k++) wreg[k] = *(const float4*)&W[k * DD + c4];
    float4 bias = *(const float4*)&b[c4];
    int rbase = blockIdx.x * 128 + (t >> 5);
#pragma unroll
    for (int it = 0; it < 16; it++) {
        int row = rbase + it * 8;
        if (row >= NN) break;
        const float4* xr = (const float4*)(x + (size_t)row * FINN);
        float4 x0 = xr[0], x1 = xr[1], x2 = xr[2], x3 = xr[3];
        float xs[16] = {x0.x, x0.y, x0.z, x0.w, x1.x, x1.y, x1.z, x1.w,
                        x2.x, x2.y, x2.z, x2.w, x3.x, x3.y, x3.z, x3.w};
        float4 acc = bias;
#pragma unroll
        for (int k = 0; k < 16; k++) {
            acc.x += xs[k] * wreg[k].x;
            acc.y += xs[k] * wreg[k].y;
            acc.z += xs[k] * wreg[k].z;
            acc.w += xs[k] * wreg[k].w;
        }
        *(float4*)&out[(size_t)row * DD + c4] = acc;
    }
}

// ------- pack 9 weight matrices into MFMA B-fragment layout, hi+lo split -------
__global__ void prep_w_kernel(const float* __restrict__ initW, const float* __restrict__ W1,
                              const float* __restrict__ W2, bf16x8* __restrict__ Wph,
                              bf16x8* __restrict__ Wpl) {
    int tid = blockIdx.x * 256 + threadIdx.x;  // 9*2048 = 18432
    if (tid >= 9 * 2048) return;
    int mat = tid >> 11;
    int rem = tid & 2047;
    int kk = rem >> 9;
    int c = (rem >> 6) & 7;
    int lane = rem & 63;
    const float* Wm;
    if (mat == 0) Wm = initW;
    else if (mat <= 4) Wm = W1 + (size_t)(mat - 1) * DD * DD;
    else Wm = W2 + (size_t)(mat - 5) * DD * DD;
    int col = c * 16 + (lane & 15);
    int kbase = kk * 32 + (lane >> 4) * 8;
    bf16x8 oh, ol;
#pragma unroll
    for (int j = 0; j < 8; j++) {
        float v = Wm[(size_t)(kbase + j) * DD + col];
        short h = bfr(v);
        oh[j] = h;
        ol[j] = bfr(v - bf2f(h));
    }
    Wph[tid] = oh;
    Wpl[tid] = ol;
}

// ---------------- fold BN into per-column scale/bias ----------------
__global__ void prep_scb_kernel(const float* __restrict__ initb,
                                const float* __restrict__ b1, const float* __restrict__ g1,
                                const float* __restrict__ be1, const float* __restrict__ rm1,
                                const float* __restrict__ rv1,
                                const float* __restrict__ b2, const float* __restrict__ g2,
                                const float* __restrict__ be2, const float* __restrict__ rm2,
                                const float* __restrict__ rv2,
                                float* __restrict__ sc, float* __restrict__ bb) {
    int tid = blockIdx.x * 256 + threadIdx.x;  // 9*128
    if (tid >= 9 * DD) return;
    int mat = tid >> 7, d = tid & 127;
    float s, o;
    if (mat == 0) {
        s = 1.f;
        o = initb[d];
    } else {
        const float *b_, *g_, *be_, *rm_, *rv_;
        int i;
        if (mat <= 4) { i = mat - 1; b_ = b1; g_ = g1; be_ = be1; rm_ = rm1; rv_ = rv1; }
        else          { i = mat - 5; b_ = b2; g_ = g2; be_ = be2; rm_ = rm2; rv_ = rv2; }
        float t = g_[i * DD + d] * rsqrtf(rv_[i * DD + d] + BN_EPS);
        s = t;
        o = (b_[i * DD + d] - rm_[i * DD + d]) * t + be_[i * DD + d];
    }
    sc[tid] = s;
    bb[tid] = o;
}

// ---------------- CSR build ----------------
__global__ void zero_int_kernel(int* __restrict__ p, int n) {
    int i = blockIdx.x * 256 + threadIdx.x;
    if (i < n) p[i] = 0;
}

__global__ void hist_kernel(const int* __restrict__ dst, int* __restrict__ deg) {
    int e = blockIdx.x * 256 + threadIdx.x;
    if (e < NE) atomicAdd(&deg[dst[e]], 1);
}

__global__ void scan_reduce_kernel(const int* __restrict__ deg, int* __restrict__ bsum) {
    __shared__ int s[256];
    int b = blockIdx.x, t = threadIdx.x;
    int base = b * 1024 + t * 4;
    int v = 0;
#pragma unroll
    for (int i = 0; i < 4; i++) {
        int idx = base + i;
        if (idx < NN) v += deg[idx];
    }
    s[t] = v;
    __syncthreads();
    for (int off = 128; off > 0; off >>= 1) {
        if (t < off) s[t] += s[t + off];
        __syncthreads();
    }
    if (t == 0) bsum[b] = s[0];
}

__global__ void scan_mid_kernel(const int* __restrict__ bsum, int* __restrict__ boff,
                                int* __restrict__ rowptrN) {
    __shared__ int s[256];
    int t = threadIdx.x;
    int v = (t < NB_SCAN) ? bsum[t] : 0;
    s[t] = v;
    __syncthreads();
    for (int off = 1; off < 256; off <<= 1) {
        int u = (t >= off) ? s[t - off] : 0;
        __syncthreads();
        s[t] += u;
        __syncthreads();
    }
    if (t < NB_SCAN) boff[t] = s[t] - v;
    if (t == 255) *rowptrN = s[255];
}

__global__ void scan_final_kernel(const int* __restrict__ deg, const int* __restrict__ boff,
                                  int* __restrict__ rowptr) {
    __shared__ int s[256];
    int b = blockIdx.x, t = threadIdx.x;
    int base = b * 1024 + t * 4;
    int v[4];
    int sum = 0;
#pragma unroll
    for (int i = 0; i < 4; i++) {
        int idx = base + i;
        v[i] = (idx < NN) ? deg[idx] : 0;
        sum += v[i];
    }
    s[t] = sum;
    __syncthreads();
    int my = sum;
    for (int off = 1; off < 256; off <<= 1) {
        int u = (t >= off) ? s[t - off] : 0;
        __syncthreads();
        s[t] += u;
        __syncthreads();
    }
    int excl = s[t] - my + boff[b];
#pragma unroll
    for (int i = 0; i < 4; i++) {
        int idx = base + i;
        if (idx < NN) rowptr[idx] = excl;
        excl += v[i];
    }
}

__global__ void copy_int_kernel(const int* __restrict__ a, int* __restrict__ b, int n) {
    int i = blockIdx.x * 256 + threadIdx.x;
    if (i < n) b[i] = a[i];
}

__global__ void fill_kernel(const int* __restrict__ src, const int* __restrict__ dst,
                            int* cursor, int* __restrict__ csr_src) {
    int e = blockIdx.x * 256 + threadIdx.x;
    if (e >= NE) return;
    int p = atomicAdd(&cursor[dst[e]], 1);
    csr_src[p] = src[e];
}

// ---------------- graph segment starts (batch sorted) ----------------
__global__ void gstart_kernel(const int* __restrict__ batch, int* __restrict__ gstart) {
    int n = blockIdx.x * 256 + threadIdx.x;
    if (n >= NN) return;
    int b = batch[n];
    int prev = (n == 0) ? -1 : batch[n - 1];
    for (int g = prev + 1; g <= b; g++) gstart[g] = n;
    if (n == NN - 1) {
        for (int g = b + 1; g <= NG; g++) gstart[g] = NN;
    }
}

// ------- fused GIN aggregation: B[n] = (1+eps)*A[n] + sum_{j in N(n)} A[j] -------
// ONE ROW PER WAVE: 64 lanes x f32x2 = full 512B row per instruction.
__global__ __launch_bounds__(256) void agg_kernel(const float* __restrict__ A,
                                                  const int* __restrict__ rowptr,
                                                  const int* __restrict__ csr_src,
                                                  const float* __restrict__ gin_eps,
                                                  int li, float* __restrict__ B) {
    int n = __builtin_amdgcn_readfirstlane(blockIdx.x * 4 + (threadIdx.x >> 6));
    int c2 = (threadIdx.x & 63) * 2;
    float e1 = 1.f + gin_eps[li];
    int s = __builtin_amdgcn_readfirstlane(rowptr[n]);
    int e = __builtin_amdgcn_readfirstlane(rowptr[n + 1]);
    f32x2 acc = *(const f32x2*)&A[(size_t)n * DD + c2] * e1;
    int i = s;
    for (; i + 8 <= e; i += 8) {
        int j0 = __builtin_amdgcn_readfirstlane(csr_src[i + 0]);
        int j1 = __builtin_amdgcn_readfirstlane(csr_src[i + 1]);
        int j2 = __builtin_amdgcn_readfirstlane(csr_src[i + 2]);
        int j3 = __builtin_amdgcn_readfirstlane(csr_src[i + 3]);
        int j4 = __builtin_amdgcn_readfirstlane(csr_src[i + 4]);
        int j5 = __builtin_amdgcn_readfirstlane(csr_src[i + 5]);
        int j6 = __builtin_amdgcn_readfirstlane(csr_src[i + 6]);
        int j7 = __builtin_amdgcn_readfirstlane(csr_src[i + 7]);
        f32x2 v0 = *(const f32x2*)&A[(size_t)j0 * DD + c2];
        f32x2 v1 = *(const f32x2*)&A[(size_t)j1 * DD + c2];
        f32x2 v2 = *(const f32x2*)&A[(size_t)j2 * DD + c2];
        f32x2 v3 = *(const f32x2*)&A[(size_t)j3 * DD + c2];
        f32x2 v4 = *(const f32x2*)&A[(size_t)j4 * DD + c2];
        f32x2 v5 = *(const f32x2*)&A[(size_t)j5 * DD + c2];
        f32x2 v6 = *(const f32x2*)&A[(size_t)j6 * DD + c2];
        f32x2 v7 = *(const f32x2*)&A[(size_t)j7 * DD + c2];
        acc += ((v0 + v1) + (v2 + v3)) + ((v4 + v5) + (v6 + v7));
    }
    if (i + 4 <= e) {
        int j0 = __builtin_amdgcn_readfirstlane(csr_src[i + 0]);
        int j1 = __builtin_amdgcn_readfirstlane(csr_src[i + 1]);
        int j2 = __builtin_amdgcn_readfirstlane(csr_src[i + 2]);
        int j3 = __builtin_amdgcn_readfirstlane(csr_src[i + 3]);
        f32x2 v0 = *(const f32x2*)&A[(size_t)j0 * DD + c2];
        f32x2 v1 = *(const f32x2*)&A[(size_t)j1 * DD + c2];
        f32x2 v2 = *(const f32x2*)&A[(size_t)j2 * DD + c2];
        f32x2 v3 = *(const f32x2*)&A[(size_t)j3 * DD + c2];
        acc += (v0 + v1) + (v2 + v3);
        i += 4;
    }
    for (; i < e; i++) {
        int j = __builtin_amdgcn_readfirstlane(csr_src[i]);
        acc += *(const f32x2*)&A[(size_t)j * DD + c2];
    }
    *(f32x2*)&B[(size_t)n * DD + c2] = acc;
}

// ------- split-bf16 MFMA GEMM: C = act(sc*(A@W) + bb), A fp32 [NP,128] -------
template <int RELU>
__global__ __launch_bounds__(256) void mm_kernel(const float* __restrict__ A,
                                                 float* __restrict__ C,
                                                 const bf16x8* __restrict__ Wph,
                                                 const bf16x8* __restrict__ Wpl,
                                                 const float* __restrict__ sc,
                                                 const float* __restrict__ bb) {
    int lane = threadIdx.x & 63;
    int wid = threadIdx.x >> 6;
    int row0 = blockIdx.x * 128 + wid * 32;
    int r16 = lane & 15;
    int kg = lane >> 4;
    f32x4 acc[2][8];
#pragma unroll
    for (int m = 0; m < 2; m++)
#pragma unroll
        for (int c = 0; c < 8; c++) acc[m][c] = (f32x4){0.f, 0.f, 0.f, 0.f};
#pragma unroll
    for (int kk = 0; kk < 4; kk++) {
        bf16x8 ah[2], al[2];
#pragma unroll
        for (int m = 0; m < 2; m++) {
            const float* ap = A + (size_t)(row0 + m * 16 + r16) * DD + kk * 32 + kg * 8;
            float4 lo = *(const float4*)ap;
            float4 hi = *(const float4*)(ap + 4);
            float v[8] = {lo.x, lo.y, lo.z, lo.w, hi.x, hi.y, hi.z, hi.w};
            bf16x8 th, tl;
#pragma unroll
            for (int j = 0; j < 8; j++) {
                short h = bfr(v[j]);
                th[j] = h;
                tl[j] = bfr(v[j] - bf2f(h));
            }
            ah[m] = th;
            al[m] = tl;
        }
#pragma unroll
        for (int c = 0; c < 8; c++) {
            bf16x8 wh = Wph[kk * 512 + c * 64 + lane];
            bf16x8 wl = Wpl[kk * 512 + c * 64 + lane];
#pragma unroll
            for (int m = 0; m < 2; m++) {
                acc[m][c] = __builtin_amdgcn_mfma_f32_16x16x32_bf16(ah[m], wh, acc[m][c], 0, 0, 0);
                acc[m][c] = __builtin_amdgcn_mfma_f32_16x16x32_bf16(al[m], wh, acc[m][c], 0, 0, 0);
                acc[m][c] = __builtin_amdgcn_mfma_f32_16x16x32_bf16(ah[m], wl, acc[m][c], 0, 0, 0);
            }
        }
    }
#pragma unroll
    for (int c = 0; c < 8; c++) {
        int col = c * 16 + r16;
        float s = sc[col], o = bb[col];
#pragma unroll
        for (int m = 0; m < 2; m++) {
            int rbase = row0 + m * 16 + kg * 4;
#pragma unroll
            for (int j = 0; j < 4; j++) {
                int row = rbase + j;
                if (row < NN) {
                    float v = acc[m][c][j] * s + o;
                    if (RELU) v = fmaxf(v, 0.f);
                    C[(size_t)row * DD + col] = v;
                }
            }
        }
    }
}

// ------- fused double GEMM: Aout = relu(bn2( relu(bn1(Ain@W1)) @ W2 ))  -------
// h exchange is INTRA-WAVE: per-wave 16-row (8 KB) LDS buffer, reused for both
// m-halves. 32 KB LDS total, NO __syncthreads.
__global__ __launch_bounds__(256) void mm2x_kernel(
    const float* __restrict__ Ain, float* __restrict__ Aout,
    const bf16x8* __restrict__ Wph1, const bf16x8* __restrict__ Wpl1,
    const bf16x8* __restrict__ Wph2, const bf16x8* __restrict__ Wpl2,
    const float* __restrict__ sc1, const float* __restrict__ bb1,
    const float* __restrict__ sc2, const float* __restrict__ bb2) {
    __shared__ f32x4 hb[4][16 * 32];  // per-wave 16 rows x 128 cols (8 KB each)
    int lane = threadIdx.x & 63;
    int wid = threadIdx.x >> 6;
    int row0 = blockIdx.x * 128 + wid * 32;
    int r16 = lane & 15;
    int kg = lane >> 4;
    f32x4* hw = &hb[wid][0];
    float* hwf = (float*)hw;

    f32x4 acc[2][8];
#pragma unroll
    for (int m = 0; m < 2; m++)
#pragma unroll
        for (int c = 0; c < 8; c++) acc[m][c] = (f32x4){0.f, 0.f, 0.f, 0.f};

    // ---- GEMM1: Ain @ W1 (both m-halves; loads pipelined) ----
#pragma unroll
    for (int kk = 0; kk < 4; kk++) {
        bf16x8 ah[2], al[2];
#pragma unroll
        for (int m = 0; m < 2; m++) {
            const float* ap = Ain + (size_t)(row0 + m * 16 + r16) * DD + kk * 32 + kg * 8;
            float4 lo = *(const float4*)ap;
            float4 hi = *(const float4*)(ap + 4);
            float v[8] = {lo.x, lo.y, lo.z, lo.w, hi.x, hi.y, hi.z, hi.w};
            bf16x8 th, tl;
#pragma unroll
            for (int j = 0; j < 8; j++) {
                short h = bfr(v[j]);
                th[j] = h;
                tl[j] = bfr(v[j] - bf2f(h));
            }
            ah[m] = th;
            al[m] = tl;
        }
#pragma unroll
        for (int c = 0; c < 8; c++) {
            bf16x8 wh = Wph1[kk * 512 + c * 64 + lane];
            bf16x8 wl = Wpl1[kk * 512 + c * 64 + lane];
#pragma unroll
            for (int m = 0; m < 2; m++) {
                acc[m][c] = __builtin_amdgcn_mfma_f32_16x16x32_bf16(ah[m], wh, acc[m][c], 0, 0, 0);
                acc[m][c] = __builtin_amdgcn_mfma_f32_16x16x32_bf16(al[m], wh, acc[m][c], 0, 0, 0);
                acc[m][c] = __builtin_amdgcn_mfma_f32_16x16x32_bf16(ah[m], wl, acc[m][c], 0, 0, 0);
            }
        }
    }

    // ---- per m-half: epilogue1 -> wave-LDS -> GEMM2 -> epilogue2 ----
#pragma unroll
    for (int m = 0; m < 2; m++) {
        // epilogue1: relu(bn1) -> swizzled wave buffer (16 rows x 128 cols)
#pragma unroll
        for (int c = 0; c < 8; c++) {
            int col = c * 16 + r16;
            float s = sc1[col], o = bb1[col];
            int cs = col >> 2, cl = col & 3;
#pragma unroll
            for (int j = 0; j < 4; j++) {
                int rl = kg * 4 + j;  // local row 0..15
                float v = fmaxf(acc[m][c][j] * s + o, 0.f);
                hwf[rl * 128 + ((cs ^ (rl & 7)) << 2) + cl] = v;
            }
        }

        // GEMM2 over this half's 16 rows
        f32x4 acc2[8];
#pragma unroll
        for (int c = 0; c < 8; c++) acc2[c] = (f32x4){0.f, 0.f, 0.f, 0.f};
#pragma unroll
        for (int kk = 0; kk < 4; kk++) {
            int c0 = kk * 8 + kg * 2;
            int sw = r16 & 7;
            f32x4 lo = hw[r16 * 32 + (c0 ^ sw)];
            f32x4 hi = hw[r16 * 32 + ((c0 + 1) ^ sw)];
            float v[8] = {lo[0], lo[1], lo[2], lo[3], hi[0], hi[1], hi[2], hi[3]};
            bf16x8 th, tl;
#pragma unroll
            for (int j = 0; j < 8; j++) {
                short h = bfr(v[j]);
                th[j] = h;
                tl[j] = bfr(v[j] - bf2f(h));
            }
#pragma unroll
            for (int c = 0; c < 8; c++) {
                bf16x8 wh = Wph2[kk * 512 + c * 64 + lane];
                bf16x8 wl = Wpl2[kk * 512 + c * 64 + lane];
                acc2[c] = __builtin_amdgcn_mfma_f32_16x16x32_bf16(th, wh, acc2[c], 0, 0, 0);
                acc2[c] = __builtin_amdgcn_mfma_f32_16x16x32_bf16(tl, wh, acc2[c], 0, 0, 0);
                acc2[c] = __builtin_amdgcn_mfma_f32_16x16x32_bf16(th, wl, acc2[c], 0, 0, 0);
            }
        }

        // epilogue2: relu(bn2) -> global
#pragma unroll
        for (int c = 0; c < 8; c++) {
            int col = c * 16 + r16;
            float s = sc2[col], o = bb2[col];
            int rbase = row0 + m * 16 + kg * 4;
#pragma unroll
            for (int j = 0; j < 4; j++) {
                int row = rbase + j;
                if (row < NN) {
                    Aout[(size_t)row * DD + col] = fmaxf(acc2[c][j] * s + o, 0.f);
                }
            }
        }
    }
}

// ---------------- pool (range-based) -> OUT[g][d] = max ----------------
__global__ void pool0_kernel(const float* __restrict__ X, const int* __restrict__ gstart,
                             float* __restrict__ OUT) {
    int gph = blockIdx.x;
    int d = threadIdx.x;  // 128
    int start = gstart[gph], end = gstart[gph + 1];
    float m;
    if (start >= end) {
        m = 0.f;
    } else {
        m = -INFINITY;
        for (int n = start; n < end; n++) m = fmaxf(m, X[(size_t)n * DD + d]);
    }
    OUT[(size_t)gph * DD + d] = m;
}

// ------- fused pool + linear-accumulate: OUT[g] += max_pool(X,g) @ W + b -------
__global__ __launch_bounds__(128) void poollin_kernel(const float* __restrict__ X,
                                                      const int* __restrict__ gstart,
                                                      const float* __restrict__ W,
                                                      const float* __restrict__ b,
                                                      float* __restrict__ OUT) {
    __shared__ float p[4][DD];
    int g0 = blockIdx.x * 4;
    int d = threadIdx.x;
#pragma unroll
    for (int gg = 0; gg < 4; gg++) {
        int start = gstart[g0 + gg], end = gstart[g0 + gg + 1];
        float m;
        if (start >= end) {
            m = 0.f;
        } else {
            m = -INFINITY;
            for (int n = start; n < end; n++) m = fmaxf(m, X[(size_t)n * DD + d]);
        }
        p[gg][d] = m;
    }
    __syncthreads();
    float acc0 = b[d], acc1 = b[d], acc2 = b[d], acc3 = b[d];
#pragma unroll 8
    for (int k = 0; k < DD; k++) {
        float w = W[k * DD + d];
        acc0 += p[0][k] * w;
        acc1 += p[1][k] * w;
        acc2 += p[2][k] * w;
        acc3 += p[3][k] * w;
    }
    OUT[(size_t)(g0 + 0) * DD + d] += acc0;
    OUT[(size_t)(g0 + 1) * DD + d] += acc1;
    OUT[(size_t)(g0 + 2) * DD + d] += acc2;
    OUT[(size_t)(g0 + 3) * DD + d] += acc3;
}

// ---------------- post MLP -> scalar per graph ----------------
__global__ void post_kernel(const float* __restrict__ OUT, const float* __restrict__ W1,
                            const float* __restrict__ b1, const float* __restrict__ W2,
                            const float* __restrict__ b2, float* __restrict__ S) {
    __shared__ float o[DD];
    __shared__ float red[2];
    int gph = blockIdx.x, d = threadIdx.x;
    o[d] = fmaxf(OUT[(size_t)gph * DD + d], 0.f);
    __syncthreads();
    float acc = b1[d];
#pragma unroll 8
    for (int k = 0; k < DD; k++) acc += o[k] * W1[k * DD + d];
    acc = fmaxf(acc, 0.f);
    float v = acc * W2[d];
#pragma unroll
    for (int off = 32; off > 0; off >>= 1) v += __shfl_down(v, off);
    if ((d & 63) == 0) red[d >> 6] = v;
    __syncthreads();
    if (d == 0) S[gph] = red[0] + red[1] + b2[0];
}

// ---------------- decode ----------------
__global__ void pred_kernel(const int* __restrict__ eil, const int* __restrict__ el,
                            const float* __restrict__ S, float* __restrict__ out) {
    int i = blockIdx.x * blockDim.x + threadIdx.x;
    if (i >= NEL) return;
    int a = eil[i], b = eil[NEL + i];
    out[i] = S[a] * S[b];
    out[NEL + i] = (float)el[i];
}

extern "C" void kernel_launch(void* const* d_in, const int* in_sizes, int n_in,
                              void* d_out, int out_size, void* d_ws, size_t ws_size,
                              hipStream_t stream) {
    const float* x = (const float*)d_in[0];
    const int* edge_index = (const int*)d_in[1];
    const int* batch = (const int*)d_in[2];
    const int* eil = (const int*)d_in[3];
    const int* el = (const int*)d_in[4];
    const float* encW = (const float*)d_in[5];
    const float* encb = (const float*)d_in[6];
    const float* initW = (const float*)d_in[7];
    const float* initb = (const float*)d_in[8];
    const float* gin_eps = (const float*)d_in[9];
    const float* W1 = (const float*)d_in[10];
    const float* b1 = (const float*)d_in[11];
    const float* g1 = (const float*)d_in[12];
    const float* be1 = (const float*)d_in[13];
    const float* rm1 = (const float*)d_in[14];
    const float* rv1 = (const float*)d_in[15];
    const float* W2 = (const float*)d_in[16];
    const float* b2 = (const float*)d_in[17];
    const float* g2 = (const float*)d_in[18];
    const float* be2 = (const float*)d_in[19];
    const float* rm2 = (const float*)d_in[20];
    const float* rv2 = (const float*)d_in[21];
    const float* linW = (const float*)d_in[22];
    const float* linb = (const float*)d_in[23];
    const float* postW1 = (const float*)d_in[24];
    const float* postb1 = (const float*)d_in[25];
    const float* postW2 = (const float*)d_in[26];
    const float* postb2 = (const float*)d_in[27];

    const int* srcArr = edge_index;
    const int* dstArr = edge_index + NE;

    // workspace carve (256B aligned)
    char* w = (char*)d_ws;
    auto carve = [&](size_t bytes) -> char* {
        char* p = w;
        w += (bytes + 255) & ~(size_t)255;
        return p;
    };
    float* A = (float*)carve((size_t)NP * DD * 4);
    float* B = (float*)carve((size_t)NP * DD * 4);
    float* OUTb = (float*)carve((size_t)NG * DD * 4);
    float* S = (float*)carve((size_t)NG * 4);
    int* deg = (int*)carve((size_t)NN * 4);
    int* rowptr = (int*)carve((size_t)(NN + 1) * 4);
    int* cursor = (int*)carve((size_t)NN * 4);
    int* csr_src = (int*)carve((size_t)NE * 4);
    int* bsum = (int*)carve((size_t)NB_SCAN * 4);
    int* boff = (int*)carve((size_t)NB_SCAN * 4);
    int* gstart = (int*)carve((size_t)(NG + 1) * 4);
    bf16x8* Wph = (bf16x8*)carve((size_t)9 * 2048 * 16);
    bf16x8* Wpl = (bf16x8*)carve((size_t)9 * 2048 * 16);
    float* scv = (float*)carve((size_t)9 * DD * 4);
    float* bbv = (float*)carve((size_t)9 * DD * 4);

    float* out = (float*)d_out;
    const int mmBlk = NP / 128;  // 1172

    // ---- prep (weights pack + BN fold) ----
    prep_w_kernel<<<72, 256, 0, stream>>>(initW, W1, W2, Wph, Wpl);
    prep_scb_kernel<<<5, 256, 0, stream>>>(initb, b1, g1, be1, rm1, rv1,
                                           b2, g2, be2, rm2, rv2, scv, bbv);

    // ---- CSR build (once, reused across 4 layers) ----
    zero_int_kernel<<<586, 256, 0, stream>>>(deg, NN);
    hist_kernel<<<2344, 256, 0, stream>>>(dstArr, deg);
    scan_reduce_kernel<<<NB_SCAN, 256, 0, stream>>>(deg, bsum);
    scan_mid_kernel<<<1, 256, 0, stream>>>(bsum, boff, rowptr + NN);
    scan_final_kernel<<<NB_SCAN, 256, 0, stream>>>(deg, boff, rowptr);
    copy_int_kernel<<<586, 256, 0, stream>>>(rowptr, cursor, NN);
    fill_kernel<<<2344, 256, 0, stream>>>(srcArr, dstArr, cursor, csr_src);
    gstart_kernel<<<586, 256, 0, stream>>>(batch, gstart);

    // ---- encoder -> A ----
    enc_kernel<<<mmBlk, 256, 0, stream>>>(x, encW, encb, A);
    // B = A @ initW + initb   (mat 0, no relu)
    mm_kernel<0><<<mmBlk, 256, 0, stream>>>(A, B, Wph, Wpl, scv, bbv);
    // OUT = pool(B)
    pool0_kernel<<<NG, DD, 0, stream>>>(B, gstart, OUTb);

    for (int i = 0; i < NL; i++) {
        // B = (1+eps)*A + CSR-sum(A)   (one row per wave)
        agg_kernel<<<NN / 4, 256, 0, stream>>>(A, rowptr, csr_src, gin_eps, i, B);
        // A = relu(bn2( relu(bn1(B@W1)) @ W2 ))  — fused, per-wave LDS
        mm2x_kernel<<<mmBlk, 256, 0, stream>>>(
            B, A,
            Wph + (size_t)(1 + i) * 2048, Wpl + (size_t)(1 + i) * 2048,
            Wph + (size_t)(5 + i) * 2048, Wpl + (size_t)(5 + i) * 2048,
            scv + (1 + i) * DD, bbv + (1 + i) * DD,
            scv + (5 + i) * DD, bbv + (5 + i) * DD);
        // OUT += pool(A) @ linW + linb
        poollin_kernel<<<NG / 4, DD, 0, stream>>>(A, gstart, linW + (size_t)i * DD * DD,
                                                  linb + i * DD, OUTb);
    }

    post_kernel<<<NG, DD, 0, stream>>>(OUTb, postW1, postb1, postW2, postb2, S);
    pred_kernel<<<(NEL + 255) / 256, 256, 0, stream>>>(eil, el, S, out);
}

// Round 12
// 1006.782 us; speedup vs baseline: 1.2486x; 1.2486x over previous
//
#include <hip/hip_runtime.h>

#define NN 150000
#define NP 150016   // NN padded to multiple of 128
#define NE 600000
#define NG 8192
#define DD 128
#define FINN 16
#define NL 4
#define NEL 500000
#define BN_EPS 1e-5f
#define NB_SCAN 147  // ceil(NN/1024)

typedef __attribute__((ext_vector_type(8))) short bf16x8;
typedef __attribute__((ext_vector_type(4))) float f32x4;
typedef __attribute__((ext_vector_type(2))) float f32x2;

__device__ inline short bfr(float x) {
    unsigned u = __builtin_bit_cast(unsigned, x);
    unsigned r = u + 0x7fffu + ((u >> 16) & 1u);
    return (short)(r >> 16);
}
__device__ inline float bf2f(short h) {
    return __builtin_bit_cast(float, ((unsigned)(unsigned short)h) << 16);
}

// ---------------- encoder: A[n][d] = x[n][:16] @ encW + encb ----------------
__global__ __launch_bounds__(256) void enc_kernel(const float* __restrict__ x,
                                                  const float* __restrict__ W,
                                                  const float* __restrict__ b,
                                                  float* __restrict__ out) {
    int t = threadIdx.x;
    int c4 = (t & 31) * 4;
    float4 wreg[16];
#pragma unroll
    for (int k = 0; k < 16; k++) wreg[k] = *(const float4*)&W[k * DD + c4];
    float4 bias = *(const float4*)&b[c4];
    int rbase = blockIdx.x * 128 + (t >> 5);
#pragma unroll
    for (int it = 0; it < 16; it++) {
        int row = rbase + it * 8;
        if (row >= NN) break;
        const float4* xr = (const float4*)(x + (size_t)row * FINN);
        float4 x0 = xr[0], x1 = xr[1], x2 = xr[2], x3 = xr[3];
        float xs[16] = {x0.x, x0.y, x0.z, x0.w, x1.x, x1.y, x1.z, x1.w,
                        x2.x, x2.y, x2.z, x2.w, x3.x, x3.y, x3.z, x3.w};
        float4 acc = bias;
#pragma unroll
        for (int k = 0; k < 16; k++) {
            acc.x += xs[k] * wreg[k].x;
            acc.y += xs[k] * wreg[k].y;
            acc.z += xs[k] * wreg[k].z;
            acc.w += xs[k] * wreg[k].w;
        }
        *(float4*)&out[(size_t)row * DD + c4] = acc;
    }
}

// ------- pack 9 weight matrices into MFMA B-fragment layout, hi+lo split -------
__global__ void prep_w_kernel(const float* __restrict__ initW, const float* __restrict__ W1,
                              const float* __restrict__ W2, bf16x8* __restrict__ Wph,
                              bf16x8* __restrict__ Wpl) {
    int tid = blockIdx.x * 256 + threadIdx.x;  // 9*2048 = 18432
    if (tid >= 9 * 2048) return;
    int mat = tid >> 11;
    int rem = tid & 2047;
    int kk = rem >> 9;
    int c = (rem >> 6) & 7;
    int lane = rem & 63;
    const float* Wm;
    if (mat == 0) Wm = initW;
    else if (mat <= 4) Wm = W1 + (size_t)(mat - 1) * DD * DD;
    else Wm = W2 + (size_t)(mat - 5) * DD * DD;
    int col = c * 16 + (lane & 15);
    int kbase = kk * 32 + (lane >> 4) * 8;
    bf16x8 oh, ol;
#pragma unroll
    for (int j = 0; j < 8; j++) {
        float v = Wm[(size_t)(kbase + j) * DD + col];
        short h = bfr(v);
        oh[j] = h;
        ol[j] = bfr(v - bf2f(h));
    }
    Wph[tid] = oh;
    Wpl[tid] = ol;
}

// ---------------- fold BN into per-column scale/bias ----------------
__global__ void prep_scb_kernel(const float* __restrict__ initb,
                                const float* __restrict__ b1, const float* __restrict__ g1,
                                const float* __restrict__ be1, const float* __restrict__ rm1,
                                const float* __restrict__ rv1,
                                const float* __restrict__ b2, const float* __restrict__ g2,
                                const float* __restrict__ be2, const float* __restrict__ rm2,
                                const float* __restrict__ rv2,
                                float* __restrict__ sc, float* __restrict__ bb) {
    int tid = blockIdx.x * 256 + threadIdx.x;  // 9*128
    if (tid >= 9 * DD) return;
    int mat = tid >> 7, d = tid & 127;
    float s, o;
    if (mat == 0) {
        s = 1.f;
        o = initb[d];
    } else {
        const float *b_, *g_, *be_, *rm_, *rv_;
        int i;
        if (mat <= 4) { i = mat - 1; b_ = b1; g_ = g1; be_ = be1; rm_ = rm1; rv_ = rv1; }
        else          { i = mat - 5; b_ = b2; g_ = g2; be_ = be2; rm_ = rm2; rv_ = rv2; }
        float t = g_[i * DD + d] * rsqrtf(rv_[i * DD + d] + BN_EPS);
        s = t;
        o = (b_[i * DD + d] - rm_[i * DD + d]) * t + be_[i * DD + d];
    }
    sc[tid] = s;
    bb[tid] = o;
}

// ---------------- CSR build ----------------
__global__ void zero_int_kernel(int* __restrict__ p, int n) {
    int i = blockIdx.x * 256 + threadIdx.x;
    if (i < n) p[i] = 0;
}

__global__ void hist_kernel(const int* __restrict__ dst, int* __restrict__ deg) {
    int e = blockIdx.x * 256 + threadIdx.x;
    if (e < NE) atomicAdd(&deg[dst[e]], 1);
}

__global__ void scan_reduce_kernel(const int* __restrict__ deg, int* __restrict__ bsum) {
    __shared__ int s[256];
    int b = blockIdx.x, t = threadIdx.x;
    int base = b * 1024 + t * 4;
    int v = 0;
#pragma unroll
    for (int i = 0; i < 4; i++) {
        int idx = base + i;
        if (idx < NN) v += deg[idx];
    }
    s[t] = v;
    __syncthreads();
    for (int off = 128; off > 0; off >>= 1) {
        if (t < off) s[t] += s[t + off];
        __syncthreads();
    }
    if (t == 0) bsum[b] = s[0];
}

__global__ void scan_mid_kernel(const int* __restrict__ bsum, int* __restrict__ boff,
                                int* __restrict__ rowptrN) {
    __shared__ int s[256];
    int t = threadIdx.x;
    int v = (t < NB_SCAN) ? bsum[t] : 0;
    s[t] = v;
    __syncthreads();
    for (int off = 1; off < 256; off <<= 1) {
        int u = (t >= off) ? s[t - off] : 0;
        __syncthreads();
        s[t] += u;
        __syncthreads();
    }
    if (t < NB_SCAN) boff[t] = s[t] - v;
    if (t == 255) *rowptrN = s[255];
}

__global__ void scan_final_kernel(const int* __restrict__ deg, const int* __restrict__ boff,
                                  int* __restrict__ rowptr) {
    __shared__ int s[256];
    int b = blockIdx.x, t = threadIdx.x;
    int base = b * 1024 + t * 4;
    int v[4];
    int sum = 0;
#pragma unroll
    for (int i = 0; i < 4; i++) {
        int idx = base + i;
        v[i] = (idx < NN) ? deg[idx] : 0;
        sum += v[i];
    }
    s[t] = sum;
    __syncthreads();
    int my = sum;
    for (int off = 1; off < 256; off <<= 1) {
        int u = (t >= off) ? s[t - off] : 0;
        __syncthreads();
        s[t] += u;
        __syncthreads();
    }
    int excl = s[t] - my + boff[b];
#pragma unroll
    for (int i = 0; i < 4; i++) {
        int idx = base + i;
        if (idx < NN) rowptr[idx] = excl;
        excl += v[i];
    }
}

__global__ void copy_int_kernel(const int* __restrict__ a, int* __restrict__ b, int n) {
    int i = blockIdx.x * 256 + threadIdx.x;
    if (i < n) b[i] = a[i];
}

__global__ void fill_kernel(const int* __restrict__ src, const int* __restrict__ dst,
                            int* cursor, int* __restrict__ csr_src) {
    int e = blockIdx.x * 256 + threadIdx.x;
    if (e >= NE) return;
    int p = atomicAdd(&cursor[dst[e]], 1);
    csr_src[p] = src[e];
}

// ---------------- graph segment starts (batch sorted) ----------------
__global__ void gstart_kernel(const int* __restrict__ batch, int* __restrict__ gstart) {
    int n = blockIdx.x * 256 + threadIdx.x;
    if (n >= NN) return;
    int b = batch[n];
    int prev = (n == 0) ? -1 : batch[n - 1];
    for (int g = prev + 1; g <= b; g++) gstart[g] = n;
    if (n == NN - 1) {
        for (int g = b + 1; g <= NG; g++) gstart[g] = NN;
    }
}

// ------- fused GIN aggregation: Bh[n] = bf16( (1+eps)*A[n] + sum_{j} A[j] ) -------
// ONE ROW PER WAVE: 64 lanes x f32x2 = full 512B row per gather instruction.
// Output stored as bf16 (RNE) — consumed only as GEMM1's bf16 MFMA operand.
__global__ __launch_bounds__(256) void agg_kernel(const float* __restrict__ A,
                                                  const int* __restrict__ rowptr,
                                                  const int* __restrict__ csr_src,
                                                  const float* __restrict__ gin_eps,
                                                  int li, unsigned short* __restrict__ Bh) {
    int n = __builtin_amdgcn_readfirstlane(blockIdx.x * 4 + (threadIdx.x >> 6));
    int c2 = (threadIdx.x & 63) * 2;
    float e1 = 1.f + gin_eps[li];
    int s = __builtin_amdgcn_readfirstlane(rowptr[n]);
    int e = __builtin_amdgcn_readfirstlane(rowptr[n + 1]);
    f32x2 acc = *(const f32x2*)&A[(size_t)n * DD + c2] * e1;
    int i = s;
    for (; i + 8 <= e; i += 8) {
        int j0 = __builtin_amdgcn_readfirstlane(csr_src[i + 0]);
        int j1 = __builtin_amdgcn_readfirstlane(csr_src[i + 1]);
        int j2 = __builtin_amdgcn_readfirstlane(csr_src[i + 2]);
        int j3 = __builtin_amdgcn_readfirstlane(csr_src[i + 3]);
        int j4 = __builtin_amdgcn_readfirstlane(csr_src[i + 4]);
        int j5 = __builtin_amdgcn_readfirstlane(csr_src[i + 5]);
        int j6 = __builtin_amdgcn_readfirstlane(csr_src[i + 6]);
        int j7 = __builtin_amdgcn_readfirstlane(csr_src[i + 7]);
        f32x2 v0 = *(const f32x2*)&A[(size_t)j0 * DD + c2];
        f32x2 v1 = *(const f32x2*)&A[(size_t)j1 * DD + c2];
        f32x2 v2 = *(const f32x2*)&A[(size_t)j2 * DD + c2];
        f32x2 v3 = *(const f32x2*)&A[(size_t)j3 * DD + c2];
        f32x2 v4 = *(const f32x2*)&A[(size_t)j4 * DD + c2];
        f32x2 v5 = *(const f32x2*)&A[(size_t)j5 * DD + c2];
        f32x2 v6 = *(const f32x2*)&A[(size_t)j6 * DD + c2];
        f32x2 v7 = *(const f32x2*)&A[(size_t)j7 * DD + c2];
        acc += ((v0 + v1) + (v2 + v3)) + ((v4 + v5) + (v6 + v7));
    }
    if (i + 4 <= e) {
        int j0 = __builtin_amdgcn_readfirstlane(csr_src[i + 0]);
        int j1 = __builtin_amdgcn_readfirstlane(csr_src[i + 1]);
        int j2 = __builtin_amdgcn_readfirstlane(csr_src[i + 2]);
        int j3 = __builtin_amdgcn_readfirstlane(csr_src[i + 3]);
        f32x2 v0 = *(const f32x2*)&A[(size_t)j0 * DD + c2];
        f32x2 v1 = *(const f32x2*)&A[(size_t)j1 * DD + c2];
        f32x2 v2 = *(const f32x2*)&A[(size_t)j2 * DD + c2];
        f32x2 v3 = *(const f32x2*)&A[(size_t)j3 * DD + c2];
        acc += (v0 + v1) + (v2 + v3);
        i += 4;
    }
    for (; i < e; i++) {
        int j = __builtin_amdgcn_readfirstlane(csr_src[i]);
        acc += *(const f32x2*)&A[(size_t)j * DD + c2];
    }
    unsigned lo = (unsigned)(unsigned short)bfr(acc[0]);
    unsigned hi = (unsigned)(unsigned short)bfr(acc[1]);
    *(unsigned*)&Bh[(size_t)n * DD + c2] = lo | (hi << 16);
}

// ------- split-bf16 MFMA GEMM: C = act(sc*(A@W) + bb), A fp32 [NP,128] -------
template <int RELU>
__global__ __launch_bounds__(256) void mm_kernel(const float* __restrict__ A,
                                                 float* __restrict__ C,
                                                 const bf16x8* __restrict__ Wph,
                                                 const bf16x8* __restrict__ Wpl,
                                                 const float* __restrict__ sc,
                                                 const float* __restrict__ bb) {
    int lane = threadIdx.x & 63;
    int wid = threadIdx.x >> 6;
    int row0 = blockIdx.x * 128 + wid * 32;
    int r16 = lane & 15;
    int kg = lane >> 4;
    f32x4 acc[2][8];
#pragma unroll
    for (int m = 0; m < 2; m++)
#pragma unroll
        for (int c = 0; c < 8; c++) acc[m][c] = (f32x4){0.f, 0.f, 0.f, 0.f};
#pragma unroll
    for (int kk = 0; kk < 4; kk++) {
        bf16x8 ah[2], al[2];
#pragma unroll
        for (int m = 0; m < 2; m++) {
            const float* ap = A + (size_t)(row0 + m * 16 + r16) * DD + kk * 32 + kg * 8;
            float4 lo = *(const float4*)ap;
            float4 hi = *(const float4*)(ap + 4);
            float v[8] = {lo.x, lo.y, lo.z, lo.w, hi.x, hi.y, hi.z, hi.w};
            bf16x8 th, tl;
#pragma unroll
            for (int j = 0; j < 8; j++) {
                short h = bfr(v[j]);
                th[j] = h;
                tl[j] = bfr(v[j] - bf2f(h));
            }
            ah[m] = th;
            al[m] = tl;
        }
#pragma unroll
        for (int c = 0; c < 8; c++) {
            bf16x8 wh = Wph[kk * 512 + c * 64 + lane];
            bf16x8 wl = Wpl[kk * 512 + c * 64 + lane];
#pragma unroll
            for (int m = 0; m < 2; m++) {
                acc[m][c] = __builtin_amdgcn_mfma_f32_16x16x32_bf16(ah[m], wh, acc[m][c], 0, 0, 0);
                acc[m][c] = __builtin_amdgcn_mfma_f32_16x16x32_bf16(al[m], wh, acc[m][c], 0, 0, 0);
                acc[m][c] = __builtin_amdgcn_mfma_f32_16x16x32_bf16(ah[m], wl, acc[m][c], 0, 0, 0);
            }
        }
    }
#pragma unroll
    for (int c = 0; c < 8; c++) {
        int col = c * 16 + r16;
        float s = sc[col], o = bb[col];
#pragma unroll
        for (int m = 0; m < 2; m++) {
            int rbase = row0 + m * 16 + kg * 4;
#pragma unroll
            for (int j = 0; j < 4; j++) {
                int row = rbase + j;
                if (row < NN) {
                    float v = acc[m][c][j] * s + o;
                    if (RELU) v = fmaxf(v, 0.f);
                    C[(size_t)row * DD + col] = v;
                }
            }
        }
    }
}

// ------- fused double GEMM: Aout = relu(bn2( relu(bn1(Bh@W1)) @ W2 ))  -------
// Bh is bf16 (agg output) -> direct MFMA fragments, GEMM1 = Bh@(Wh+Wl).
// h tile (128x128 fp32) lives in XOR-swizzled LDS; no global h round-trip.
__global__ __launch_bounds__(256) void mm2x_kernel(
    const unsigned short* __restrict__ Bh, float* __restrict__ Aout,
    const bf16x8* __restrict__ Wph1, const bf16x8* __restrict__ Wpl1,
    const bf16x8* __restrict__ Wph2, const bf16x8* __restrict__ Wpl2,
    const float* __restrict__ sc1, const float* __restrict__ bb1,
    const float* __restrict__ sc2, const float* __restrict__ bb2) {
    __shared__ float hl[128 * 128];  // phys col = logical col ^ ((row&7)<<2)
    int lane = threadIdx.x & 63;
    int wid = threadIdx.x >> 6;
    int row0 = blockIdx.x * 128 + wid * 32;
    int r16 = lane & 15;
    int kg = lane >> 4;
    f32x4 acc[2][8];
#pragma unroll
    for (int m = 0; m < 2; m++)
#pragma unroll
        for (int c = 0; c < 8; c++) acc[m][c] = (f32x4){0.f, 0.f, 0.f, 0.f};

    // ---- GEMM1: Bh @ W1 (bf16 direct fragments) ----
#pragma unroll
    for (int kk = 0; kk < 4; kk++) {
        bf16x8 ab[2];
#pragma unroll
        for (int m = 0; m < 2; m++) {
            ab[m] = *(const bf16x8*)&Bh[(size_t)(row0 + m * 16 + r16) * DD + kk * 32 + kg * 8];
        }
#pragma unroll
        for (int c = 0; c < 8; c++) {
            bf16x8 wh = Wph1[kk * 512 + c * 64 + lane];
            bf16x8 wl = Wpl1[kk * 512 + c * 64 + lane];
#pragma unroll
            for (int m = 0; m < 2; m++) {
                acc[m][c] = __builtin_amdgcn_mfma_f32_16x16x32_bf16(ab[m], wh, acc[m][c], 0, 0, 0);
                acc[m][c] = __builtin_amdgcn_mfma_f32_16x16x32_bf16(ab[m], wl, acc[m][c], 0, 0, 0);
            }
        }
    }
    // ---- epilogue1: relu(bn1) -> swizzled LDS ----
#pragma unroll
    for (int c = 0; c < 8; c++) {
        int col = c * 16 + r16;
        float s = sc1[col], o = bb1[col];
#pragma unroll
        for (int m = 0; m < 2; m++) {
#pragma unroll
            for (int j = 0; j < 4; j++) {
                int rl = wid * 32 + m * 16 + kg * 4 + j;
                float v = fmaxf(acc[m][c][j] * s + o, 0.f);
                hl[rl * 128 + (col ^ ((rl & 7) << 2))] = v;
            }
        }
    }
    __syncthreads();

    // ---- GEMM2: h @ W2 (fp32 h, split hi+lo) ----
#pragma unroll
    for (int m = 0; m < 2; m++)
#pragma unroll
        for (int c = 0; c < 8; c++) acc[m][c] = (f32x4){0.f, 0.f, 0.f, 0.f};
#pragma unroll
    for (int kk = 0; kk < 4; kk++) {
        bf16x8 ah[2], al[2];
#pragma unroll
        for (int m = 0; m < 2; m++) {
            int rl = wid * 32 + m * 16 + r16;
            int sw = (rl & 7) << 2;
            int c0 = kk * 32 + kg * 8;
            float4 lo = *(const float4*)&hl[rl * 128 + (c0 ^ sw)];
            float4 hi = *(const float4*)&hl[rl * 128 + ((c0 + 4) ^ sw)];
            float v[8] = {lo.x, lo.y, lo.z, lo.w, hi.x, hi.y, hi.z, hi.w};
            bf16x8 th, tl;
#pragma unroll
            for (int j = 0; j < 8; j++) {
                short h = bfr(v[j]);
                th[j] = h;
                tl[j] = bfr(v[j] - bf2f(h));
            }
            ah[m] = th;
            al[m] = tl;
        }
#pragma unroll
        for (int c = 0; c < 8; c++) {
            bf16x8 wh = Wph2[kk * 512 + c * 64 + lane];
            bf16x8 wl = Wpl2[kk * 512 + c * 64 + lane];
#pragma unroll
            for (int m = 0; m < 2; m++) {
                acc[m][c] = __builtin_amdgcn_mfma_f32_16x16x32_bf16(ah[m], wh, acc[m][c], 0, 0, 0);
                acc[m][c] = __builtin_amdgcn_mfma_f32_16x16x32_bf16(al[m], wh, acc[m][c], 0, 0, 0);
                acc[m][c] = __builtin_amdgcn_mfma_f32_16x16x32_bf16(ah[m], wl, acc[m][c], 0, 0, 0);
            }
        }
    }
    // ---- epilogue2: relu(bn2) -> global ----
#pragma unroll
    for (int c = 0; c < 8; c++) {
        int col = c * 16 + r16;
        float s = sc2[col], o = bb2[col];
#pragma unroll
        for (int m = 0; m < 2; m++) {
            int rbase = row0 + m * 16 + kg * 4;
#pragma unroll
            for (int j = 0; j < 4; j++) {
                int row = rbase + j;
                if (row < NN) {
                    Aout[(size_t)row * DD + col] = fmaxf(acc[m][c][j] * s + o, 0.f);
                }
            }
        }
    }
}

// ---------------- pool (range-based) -> OUT[g][d] = max ----------------
__global__ void pool0_kernel(const float* __restrict__ X, const int* __restrict__ gstart,
                             float* __restrict__ OUT) {
    int gph = blockIdx.x;
    int d = threadIdx.x;  // 128
    int start = gstart[gph], end = gstart[gph + 1];
    float m;
    if (start >= end) {
        m = 0.f;
    } else {
        m = -INFINITY;
        for (int n = start; n < end; n++) m = fmaxf(m, X[(size_t)n * DD + d]);
    }
    OUT[(size_t)gph * DD + d] = m;
}

// ------- fused pool + linear-accumulate: OUT[g] += max_pool(X,g) @ W + b -------
__global__ __launch_bounds__(128) void poollin_kernel(const float* __restrict__ X,
                                                      const int* __restrict__ gstart,
                                                      const float* __restrict__ W,
                                                      const float* __restrict__ b,
                                                      float* __restrict__ OUT) {
    __shared__ float p[4][DD];
    int g0 = blockIdx.x * 4;
    int d = threadIdx.x;
#pragma unroll
    for (int gg = 0; gg < 4; gg++) {
        int start = gstart[g0 + gg], end = gstart[g0 + gg + 1];
        float m;
        if (start >= end) {
            m = 0.f;
        } else {
            m = -INFINITY;
            for (int n = start; n < end; n++) m = fmaxf(m, X[(size_t)n * DD + d]);
        }
        p[gg][d] = m;
    }
    __syncthreads();
    float acc0 = b[d], acc1 = b[d], acc2 = b[d], acc3 = b[d];
#pragma unroll 8
    for (int k = 0; k < DD; k++) {
        float w = W[k * DD + d];
        acc0 += p[0][k] * w;
        acc1 += p[1][k] * w;
        acc2 += p[2][k] * w;
        acc3 += p[3][k] * w;
    }
    OUT[(size_t)(g0 + 0) * DD + d] += acc0;
    OUT[(size_t)(g0 + 1) * DD + d] += acc1;
    OUT[(size_t)(g0 + 2) * DD + d] += acc2;
    OUT[(size_t)(g0 + 3) * DD + d] += acc3;
}

// ---------------- post MLP -> scalar per graph ----------------
__global__ void post_kernel(const float* __restrict__ OUT, const float* __restrict__ W1,
                            const float* __restrict__ b1, const float* __restrict__ W2,
                            const float* __restrict__ b2, float* __restrict__ S) {
    __shared__ float o[DD];
    __shared__ float red[2];
    int gph = blockIdx.x, d = threadIdx.x;
    o[d] = fmaxf(OUT[(size_t)gph * DD + d], 0.f);
    __syncthreads();
    float acc = b1[d];
#pragma unroll 8
    for (int k = 0; k < DD; k++) acc += o[k] * W1[k * DD + d];
    acc = fmaxf(acc, 0.f);
    float v = acc * W2[d];
#pragma unroll
    for (int off = 32; off > 0; off >>= 1) v += __shfl_down(v, off);
    if ((d & 63) == 0) red[d >> 6] = v;
    __syncthreads();
    if (d == 0) S[gph] = red[0] + red[1] + b2[0];
}

// ---------------- decode ----------------
__global__ void pred_kernel(const int* __restrict__ eil, const int* __restrict__ el,
                            const float* __restrict__ S, float* __restrict__ out) {
    int i = blockIdx.x * blockDim.x + threadIdx.x;
    if (i >= NEL) return;
    int a = eil[i], b = eil[NEL + i];
    out[i] = S[a] * S[b];
    out[NEL + i] = (float)el[i];
}

extern "C" void kernel_launch(void* const* d_in, const int* in_sizes, int n_in,
                              void* d_out, int out_size, void* d_ws, size_t ws_size,
                              hipStream_t stream) {
    const float* x = (const float*)d_in[0];
    const int* edge_index = (const int*)d_in[1];
    const int* batch = (const int*)d_in[2];
    const int* eil = (const int*)d_in[3];
    const int* el = (const int*)d_in[4];
    const float* encW = (const float*)d_in[5];
    const float* encb = (const float*)d_in[6];
    const float* initW = (const float*)d_in[7];
    const float* initb = (const float*)d_in[8];
    const float* gin_eps = (const float*)d_in[9];
    const float* W1 = (const float*)d_in[10];
    const float* b1 = (const float*)d_in[11];
    const float* g1 = (const float*)d_in[12];
    const float* be1 = (const float*)d_in[13];
    const float* rm1 = (const float*)d_in[14];
    const float* rv1 = (const float*)d_in[15];
    const float* W2 = (const float*)d_in[16];
    const float* b2 = (const float*)d_in[17];
    const float* g2 = (const float*)d_in[18];
    const float* be2 = (const float*)d_in[19];
    const float* rm2 = (const float*)d_in[20];
    const float* rv2 = (const float*)d_in[21];
    const float* linW = (const float*)d_in[22];
    const float* linb = (const float*)d_in[23];
    const float* postW1 = (const float*)d_in[24];
    const float* postb1 = (const float*)d_in[25];
    const float* postW2 = (const float*)d_in[26];
    const float* postb2 = (const float*)d_in[27];

    const int* srcArr = edge_index;
    const int* dstArr = edge_index + NE;

    // workspace carve (256B aligned)
    char* w = (char*)d_ws;
    auto carve = [&](size_t bytes) -> char* {
        char* p = w;
        w += (bytes + 255) & ~(size_t)255;
        return p;
    };
    float* A = (float*)carve((size_t)NP * DD * 4);
    float* B = (float*)carve((size_t)NP * DD * 4);  // fp32 init-GEMM out; later bf16 agg out
    float* OUTb = (float*)carve((size_t)NG * DD * 4);
    float* S = (float*)carve((size_t)NG * 4);
    int* deg = (int*)carve((size_t)NN * 4);
    int* rowptr = (int*)carve((size_t)(NN + 1) * 4);
    int* cursor = (int*)carve((size_t)NN * 4);
    int* csr_src = (int*)carve((size_t)NE * 4);
    int* bsum = (int*)carve((size_t)NB_SCAN * 4);
    int* boff = (int*)carve((size_t)NB_SCAN * 4);
    int* gstart = (int*)carve((size_t)(NG + 1) * 4);
    bf16x8* Wph = (bf16x8*)carve((size_t)9 * 2048 * 16);
    bf16x8* Wpl = (bf16x8*)carve((size_t)9 * 2048 * 16);
    float* scv = (float*)carve((size_t)9 * DD * 4);
    float* bbv = (float*)carve((size_t)9 * DD * 4);

    unsigned short* Bh = (unsigned short*)B;  // bf16 view (time-separated from fp32 use)

    float* out = (float*)d_out;
    const int mmBlk = NP / 128;  // 1172

    // ---- prep (weights pack + BN fold) ----
    prep_w_kernel<<<72, 256, 0, stream>>>(initW, W1, W2, Wph, Wpl);
    prep_scb_kernel<<<5, 256, 0, stream>>>(initb, b1, g1, be1, rm1, rv1,
                                           b2, g2, be2, rm2, rv2, scv, bbv);

    // ---- CSR build (once, reused across 4 layers) ----
    zero_int_kernel<<<586, 256, 0, stream>>>(deg, NN);
    hist_kernel<<<2344, 256, 0, stream>>>(dstArr, deg);
    scan_reduce_kernel<<<NB_SCAN, 256, 0, stream>>>(deg, bsum);
    scan_mid_kernel<<<1, 256, 0, stream>>>(bsum, boff, rowptr + NN);
    scan_final_kernel<<<NB_SCAN, 256, 0, stream>>>(deg, boff, rowptr);
    copy_int_kernel<<<586, 256, 0, stream>>>(rowptr, cursor, NN);
    fill_kernel<<<2344, 256, 0, stream>>>(srcArr, dstArr, cursor, csr_src);
    gstart_kernel<<<586, 256, 0, stream>>>(batch, gstart);

    // ---- encoder -> A ----
    enc_kernel<<<mmBlk, 256, 0, stream>>>(x, encW, encb, A);
    // B = A @ initW + initb   (mat 0, no relu, fp32 out)
    mm_kernel<0><<<mmBlk, 256, 0, stream>>>(A, B, Wph, Wpl, scv, bbv);
    // OUT = pool(B)
    pool0_kernel<<<NG, DD, 0, stream>>>(B, gstart, OUTb);

    for (int i = 0; i < NL; i++) {
        // Bh = bf16( (1+eps)*A + CSR-sum(A) )   (one row per wave)
        agg_kernel<<<NN / 4, 256, 0, stream>>>(A, rowptr, csr_src, gin_eps, i, Bh);
        // A = relu(bn2( relu(bn1(Bh@W1)) @ W2 ))  — fused, h in LDS
        mm2x_kernel<<<mmBlk, 256, 0, stream>>>(
            Bh, A,
            Wph + (size_t)(1 + i) * 2048, Wpl + (size_t)(1 + i) * 2048,
            Wph + (size_t)(5 + i) * 2048, Wpl + (size_t)(5 + i) * 2048,
            scv + (1 + i) * DD, bbv + (1 + i) * DD,
            scv + (5 + i) * DD, bbv + (5 + i) * DD);
        // OUT += pool(A) @ linW + linb
        poollin_kernel<<<NG / 4, DD, 0, stream>>>(A, gstart, linW + (size_t)i * DD * DD,
                                                  linb + i * DD, OUTb);
    }

    post_kernel<<<NG, DD, 0, stream>>>(OUTb, postW1, postb1, postW2, postb2, S);
    pred_kernel<<<(NEL + 255) / 256, 256, 0, stream>>>(eil, el, S, out);
}

// Round 13
// 898.212 us; speedup vs baseline: 1.3995x; 1.1209x over previous
//
#include <hip/hip_runtime.h>

#define NN 150000
#define NP 150016   // NN padded to multiple of 128
#define NE 600000
#define NG 8192
#define DD 128
#define FINN 16
#define NL 4
#define NEL 500000
#define BN_EPS 1e-5f
#define NB_SCAN 147  // ceil(NN/1024)

typedef __attribute__((ext_vector_type(8))) short bf16x8;
typedef __attribute__((ext_vector_type(4))) float f32x4;

__device__ inline short bfr(float x) {
    unsigned u = __builtin_bit_cast(unsigned, x);
    unsigned r = u + 0x7fffu + ((u >> 16) & 1u);
    return (short)(r >> 16);
}
__device__ inline float bf2f(short h) {
    return __builtin_bit_cast(float, ((unsigned)(unsigned short)h) << 16);
}
__device__ inline unsigned pack2(float a, float b) {
    return (unsigned)(unsigned short)bfr(a) | ((unsigned)(unsigned short)bfr(b) << 16);
}

// ---------------- encoder: A[n][d] = bf16(x[n][:16] @ encW + encb) ----------------
__global__ __launch_bounds__(256) void enc_kernel(const float* __restrict__ x,
                                                  const float* __restrict__ W,
                                                  const float* __restrict__ b,
                                                  unsigned short* __restrict__ out) {
    int t = threadIdx.x;
    int c4 = (t & 31) * 4;
    float4 wreg[16];
#pragma unroll
    for (int k = 0; k < 16; k++) wreg[k] = *(const float4*)&W[k * DD + c4];
    float4 bias = *(const float4*)&b[c4];
    int rbase = blockIdx.x * 128 + (t >> 5);
#pragma unroll
    for (int it = 0; it < 16; it++) {
        int row = rbase + it * 8;
        if (row >= NN) break;
        const float4* xr = (const float4*)(x + (size_t)row * FINN);
        float4 x0 = xr[0], x1 = xr[1], x2 = xr[2], x3 = xr[3];
        float xs[16] = {x0.x, x0.y, x0.z, x0.w, x1.x, x1.y, x1.z, x1.w,
                        x2.x, x2.y, x2.z, x2.w, x3.x, x3.y, x3.z, x3.w};
        float4 acc = bias;
#pragma unroll
        for (int k = 0; k < 16; k++) {
            acc.x += xs[k] * wreg[k].x;
            acc.y += xs[k] * wreg[k].y;
            acc.z += xs[k] * wreg[k].z;
            acc.w += xs[k] * wreg[k].w;
        }
        uint2 pk;
        pk.x = pack2(acc.x, acc.y);
        pk.y = pack2(acc.z, acc.w);
        *(uint2*)&out[(size_t)row * DD + c4] = pk;
    }
}

// ------- pack 9 weight matrices into MFMA B-fragment layout, hi+lo split -------
__global__ void prep_w_kernel(const float* __restrict__ initW, const float* __restrict__ W1,
                              const float* __restrict__ W2, bf16x8* __restrict__ Wph,
                              bf16x8* __restrict__ Wpl) {
    int tid = blockIdx.x * 256 + threadIdx.x;  // 9*2048 = 18432
    if (tid >= 9 * 2048) return;
    int mat = tid >> 11;
    int rem = tid & 2047;
    int kk = rem >> 9;
    int c = (rem >> 6) & 7;
    int lane = rem & 63;
    const float* Wm;
    if (mat == 0) Wm = initW;
    else if (mat <= 4) Wm = W1 + (size_t)(mat - 1) * DD * DD;
    else Wm = W2 + (size_t)(mat - 5) * DD * DD;
    int col = c * 16 + (lane & 15);
    int kbase = kk * 32 + (lane >> 4) * 8;
    bf16x8 oh, ol;
#pragma unroll
    for (int j = 0; j < 8; j++) {
        float v = Wm[(size_t)(kbase + j) * DD + col];
        short h = bfr(v);
        oh[j] = h;
        ol[j] = bfr(v - bf2f(h));
    }
    Wph[tid] = oh;
    Wpl[tid] = ol;
}

// ---------------- fold BN into per-column scale/bias ----------------
__global__ void prep_scb_kernel(const float* __restrict__ initb,
                                const float* __restrict__ b1, const float* __restrict__ g1,
                                const float* __restrict__ be1, const float* __restrict__ rm1,
                                const float* __restrict__ rv1,
                                const float* __restrict__ b2, const float* __restrict__ g2,
                                const float* __restrict__ be2, const float* __restrict__ rm2,
                                const float* __restrict__ rv2,
                                float* __restrict__ sc, float* __restrict__ bb) {
    int tid = blockIdx.x * 256 + threadIdx.x;  // 9*128
    if (tid >= 9 * DD) return;
    int mat = tid >> 7, d = tid & 127;
    float s, o;
    if (mat == 0) {
        s = 1.f;
        o = initb[d];
    } else {
        const float *b_, *g_, *be_, *rm_, *rv_;
        int i;
        if (mat <= 4) { i = mat - 1; b_ = b1; g_ = g1; be_ = be1; rm_ = rm1; rv_ = rv1; }
        else          { i = mat - 5; b_ = b2; g_ = g2; be_ = be2; rm_ = rm2; rv_ = rv2; }
        float t = g_[i * DD + d] * rsqrtf(rv_[i * DD + d] + BN_EPS);
        s = t;
        o = (b_[i * DD + d] - rm_[i * DD + d]) * t + be_[i * DD + d];
    }
    sc[tid] = s;
    bb[tid] = o;
}

// ---------------- CSR build ----------------
__global__ void zero_int_kernel(int* __restrict__ p, int n) {
    int i = blockIdx.x * 256 + threadIdx.x;
    if (i < n) p[i] = 0;
}

__global__ void hist_kernel(const int* __restrict__ dst, int* __restrict__ deg) {
    int e = blockIdx.x * 256 + threadIdx.x;
    if (e < NE) atomicAdd(&deg[dst[e]], 1);
}

__global__ void scan_reduce_kernel(const int* __restrict__ deg, int* __restrict__ bsum) {
    __shared__ int s[256];
    int b = blockIdx.x, t = threadIdx.x;
    int base = b * 1024 + t * 4;
    int v = 0;
#pragma unroll
    for (int i = 0; i < 4; i++) {
        int idx = base + i;
        if (idx < NN) v += deg[idx];
    }
    s[t] = v;
    __syncthreads();
    for (int off = 128; off > 0; off >>= 1) {
        if (t < off) s[t] += s[t + off];
        __syncthreads();
    }
    if (t == 0) bsum[b] = s[0];
}

__global__ void scan_mid_kernel(const int* __restrict__ bsum, int* __restrict__ boff,
                                int* __restrict__ rowptrN) {
    __shared__ int s[256];
    int t = threadIdx.x;
    int v = (t < NB_SCAN) ? bsum[t] : 0;
    s[t] = v;
    __syncthreads();
    for (int off = 1; off < 256; off <<= 1) {
        int u = (t >= off) ? s[t - off] : 0;
        __syncthreads();
        s[t] += u;
        __syncthreads();
    }
    if (t < NB_SCAN) boff[t] = s[t] - v;
    if (t == 255) *rowptrN = s[255];
}

__global__ void scan_final_kernel(const int* __restrict__ deg, const int* __restrict__ boff,
                                  int* __restrict__ rowptr) {
    __shared__ int s[256];
    int b = blockIdx.x, t = threadIdx.x;
    int base = b * 1024 + t * 4;
    int v[4];
    int sum = 0;
#pragma unroll
    for (int i = 0; i < 4; i++) {
        int idx = base + i;
        v[i] = (idx < NN) ? deg[idx] : 0;
        sum += v[i];
    }
    s[t] = sum;
    __syncthreads();
    int my = sum;
    for (int off = 1; off < 256; off <<= 1) {
        int u = (t >= off) ? s[t - off] : 0;
        __syncthreads();
        s[t] += u;
        __syncthreads();
    }
    int excl = s[t] - my + boff[b];
#pragma unroll
    for (int i = 0; i < 4; i++) {
        int idx = base + i;
        if (idx < NN) rowptr[idx] = excl;
        excl += v[i];
    }
}

__global__ void copy_int_kernel(const int* __restrict__ a, int* __restrict__ b, int n) {
    int i = blockIdx.x * 256 + threadIdx.x;
    if (i < n) b[i] = a[i];
}

__global__ void fill_kernel(const int* __restrict__ src, const int* __restrict__ dst,
                            int* cursor, int* __restrict__ csr_src) {
    int e = blockIdx.x * 256 + threadIdx.x;
    if (e >= NE) return;
    int p = atomicAdd(&cursor[dst[e]], 1);
    csr_src[p] = src[e];
}

// ---------------- graph segment starts (batch sorted) ----------------
__global__ void gstart_kernel(const int* __restrict__ batch, int* __restrict__ gstart) {
    int n = blockIdx.x * 256 + threadIdx.x;
    if (n >= NN) return;
    int b = batch[n];
    int prev = (n == 0) ? -1 : batch[n - 1];
    for (int g = prev + 1; g <= b; g++) gstart[g] = n;
    if (n == NN - 1) {
        for (int g = b + 1; g <= NG; g++) gstart[g] = NN;
    }
}

// ------- fused GIN aggregation: Bh[n] = bf16( (1+eps)*A[n] + sum_{j} A[j] ) -------
// ONE ROW PER WAVE: 64 lanes x bf16x2 (uint) = full 256B row per gather instruction.
__global__ __launch_bounds__(256) void agg_kernel(const unsigned short* __restrict__ A,
                                                  const int* __restrict__ rowptr,
                                                  const int* __restrict__ csr_src,
                                                  const float* __restrict__ gin_eps,
                                                  int li, unsigned short* __restrict__ Bh) {
    int n = __builtin_amdgcn_readfirstlane(blockIdx.x * 4 + (threadIdx.x >> 6));
    int c2 = (threadIdx.x & 63) * 2;
    float e1 = 1.f + gin_eps[li];
    int s = __builtin_amdgcn_readfirstlane(rowptr[n]);
    int e = __builtin_amdgcn_readfirstlane(rowptr[n + 1]);
    unsigned u = *(const unsigned*)&A[(size_t)n * DD + c2];
    float acc0 = bf2f((short)(u & 0xffff)) * e1;
    float acc1 = bf2f((short)(u >> 16)) * e1;
    int i = s;
    for (; i + 8 <= e; i += 8) {
        int j0 = __builtin_amdgcn_readfirstlane(csr_src[i + 0]);
        int j1 = __builtin_amdgcn_readfirstlane(csr_src[i + 1]);
        int j2 = __builtin_amdgcn_readfirstlane(csr_src[i + 2]);
        int j3 = __builtin_amdgcn_readfirstlane(csr_src[i + 3]);
        int j4 = __builtin_amdgcn_readfirstlane(csr_src[i + 4]);
        int j5 = __builtin_amdgcn_readfirstlane(csr_src[i + 5]);
        int j6 = __builtin_amdgcn_readfirstlane(csr_src[i + 6]);
        int j7 = __builtin_amdgcn_readfirstlane(csr_src[i + 7]);
        unsigned u0 = *(const unsigned*)&A[(size_t)j0 * DD + c2];
        unsigned u1 = *(const unsigned*)&A[(size_t)j1 * DD + c2];
        unsigned u2 = *(const unsigned*)&A[(size_t)j2 * DD + c2];
        unsigned u3 = *(const unsigned*)&A[(size_t)j3 * DD + c2];
        unsigned u4 = *(const unsigned*)&A[(size_t)j4 * DD + c2];
        unsigned u5 = *(const unsigned*)&A[(size_t)j5 * DD + c2];
        unsigned u6 = *(const unsigned*)&A[(size_t)j6 * DD + c2];
        unsigned u7 = *(const unsigned*)&A[(size_t)j7 * DD + c2];
        acc0 += ((bf2f((short)(u0 & 0xffff)) + bf2f((short)(u1 & 0xffff))) +
                 (bf2f((short)(u2 & 0xffff)) + bf2f((short)(u3 & 0xffff)))) +
                ((bf2f((short)(u4 & 0xffff)) + bf2f((short)(u5 & 0xffff))) +
                 (bf2f((short)(u6 & 0xffff)) + bf2f((short)(u7 & 0xffff))));
        acc1 += ((bf2f((short)(u0 >> 16)) + bf2f((short)(u1 >> 16))) +
                 (bf2f((short)(u2 >> 16)) + bf2f((short)(u3 >> 16)))) +
                ((bf2f((short)(u4 >> 16)) + bf2f((short)(u5 >> 16))) +
                 (bf2f((short)(u6 >> 16)) + bf2f((short)(u7 >> 16))));
    }
    if (i + 4 <= e) {
        int j0 = __builtin_amdgcn_readfirstlane(csr_src[i + 0]);
        int j1 = __builtin_amdgcn_readfirstlane(csr_src[i + 1]);
        int j2 = __builtin_amdgcn_readfirstlane(csr_src[i + 2]);
        int j3 = __builtin_amdgcn_readfirstlane(csr_src[i + 3]);
        unsigned u0 = *(const unsigned*)&A[(size_t)j0 * DD + c2];
        unsigned u1 = *(const unsigned*)&A[(size_t)j1 * DD + c2];
        unsigned u2 = *(const unsigned*)&A[(size_t)j2 * DD + c2];
        unsigned u3 = *(const unsigned*)&A[(size_t)j3 * DD + c2];
        acc0 += (bf2f((short)(u0 & 0xffff)) + bf2f((short)(u1 & 0xffff))) +
                (bf2f((short)(u2 & 0xffff)) + bf2f((short)(u3 & 0xffff)));
        acc1 += (bf2f((short)(u0 >> 16)) + bf2f((short)(u1 >> 16))) +
                (bf2f((short)(u2 >> 16)) + bf2f((short)(u3 >> 16)));
        i += 4;
    }
    for (; i < e; i++) {
        int j = __builtin_amdgcn_readfirstlane(csr_src[i]);
        unsigned uj = *(const unsigned*)&A[(size_t)j * DD + c2];
        acc0 += bf2f((short)(uj & 0xffff));
        acc1 += bf2f((short)(uj >> 16));
    }
    *(unsigned*)&Bh[(size_t)n * DD + c2] = pack2(acc0, acc1);
}

// ------- init GEMM: C = bf16(Ah @ W + bias), Ah bf16 [NP,128] -------
__global__ __launch_bounds__(256) void mm0_kernel(const unsigned short* __restrict__ Ah,
                                                  unsigned short* __restrict__ C,
                                                  const bf16x8* __restrict__ Wph,
                                                  const bf16x8* __restrict__ Wpl,
                                                  const float* __restrict__ sc,
                                                  const float* __restrict__ bb) {
    int lane = threadIdx.x & 63;
    int wid = threadIdx.x >> 6;
    int row0 = blockIdx.x * 128 + wid * 32;
    int r16 = lane & 15;
    int kg = lane >> 4;
    f32x4 acc[2][8];
#pragma unroll
    for (int m = 0; m < 2; m++)
#pragma unroll
        for (int c = 0; c < 8; c++) acc[m][c] = (f32x4){0.f, 0.f, 0.f, 0.f};
#pragma unroll
    for (int kk = 0; kk < 4; kk++) {
        bf16x8 ab[2];
#pragma unroll
        for (int m = 0; m < 2; m++)
            ab[m] = *(const bf16x8*)&Ah[(size_t)(row0 + m * 16 + r16) * DD + kk * 32 + kg * 8];
#pragma unroll
        for (int c = 0; c < 8; c++) {
            bf16x8 wh = Wph[kk * 512 + c * 64 + lane];
            bf16x8 wl = Wpl[kk * 512 + c * 64 + lane];
#pragma unroll
            for (int m = 0; m < 2; m++) {
                acc[m][c] = __builtin_amdgcn_mfma_f32_16x16x32_bf16(ab[m], wh, acc[m][c], 0, 0, 0);
                acc[m][c] = __builtin_amdgcn_mfma_f32_16x16x32_bf16(ab[m], wl, acc[m][c], 0, 0, 0);
            }
        }
    }
#pragma unroll
    for (int c = 0; c < 8; c++) {
        int col = c * 16 + r16;
        float s = sc[col], o = bb[col];
#pragma unroll
        for (int m = 0; m < 2; m++) {
            int rbase = row0 + m * 16 + kg * 4;
#pragma unroll
            for (int j = 0; j < 4; j++) {
                int row = rbase + j;
                if (row < NN)
                    C[(size_t)row * DD + col] = (unsigned short)bfr(acc[m][c][j] * s + o);
            }
        }
    }
}

// ------- fused double GEMM: Aout = bf16(relu(bn2( relu(bn1(Bh@W1)) @ W2 )))  -------
// Bh bf16 -> direct fragments; h tile fp32 in XOR-swizzled LDS.
__global__ __launch_bounds__(256) void mm2x_kernel(
    const unsigned short* __restrict__ Bh, unsigned short* __restrict__ Aout,
    const bf16x8* __restrict__ Wph1, const bf16x8* __restrict__ Wpl1,
    const bf16x8* __restrict__ Wph2, const bf16x8* __restrict__ Wpl2,
    const float* __restrict__ sc1, const float* __restrict__ bb1,
    const float* __restrict__ sc2, const float* __restrict__ bb2) {
    __shared__ float hl[128 * 128];  // phys col = logical col ^ ((row&7)<<2)
    int lane = threadIdx.x & 63;
    int wid = threadIdx.x >> 6;
    int row0 = blockIdx.x * 128 + wid * 32;
    int r16 = lane & 15;
    int kg = lane >> 4;
    f32x4 acc[2][8];
#pragma unroll
    for (int m = 0; m < 2; m++)
#pragma unroll
        for (int c = 0; c < 8; c++) acc[m][c] = (f32x4){0.f, 0.f, 0.f, 0.f};

    // ---- GEMM1: Bh @ W1 (bf16 direct fragments) ----
#pragma unroll
    for (int kk = 0; kk < 4; kk++) {
        bf16x8 ab[2];
#pragma unroll
        for (int m = 0; m < 2; m++)
            ab[m] = *(const bf16x8*)&Bh[(size_t)(row0 + m * 16 + r16) * DD + kk * 32 + kg * 8];
#pragma unroll
        for (int c = 0; c < 8; c++) {
            bf16x8 wh = Wph1[kk * 512 + c * 64 + lane];
            bf16x8 wl = Wpl1[kk * 512 + c * 64 + lane];
#pragma unroll
            for (int m = 0; m < 2; m++) {
                acc[m][c] = __builtin_amdgcn_mfma_f32_16x16x32_bf16(ab[m], wh, acc[m][c], 0, 0, 0);
                acc[m][c] = __builtin_amdgcn_mfma_f32_16x16x32_bf16(ab[m], wl, acc[m][c], 0, 0, 0);
            }
        }
    }
    // ---- epilogue1: relu(bn1) -> swizzled LDS ----
#pragma unroll
    for (int c = 0; c < 8; c++) {
        int col = c * 16 + r16;
        float s = sc1[col], o = bb1[col];
#pragma unroll
        for (int m = 0; m < 2; m++) {
#pragma unroll
            for (int j = 0; j < 4; j++) {
                int rl = wid * 32 + m * 16 + kg * 4 + j;
                float v = fmaxf(acc[m][c][j] * s + o, 0.f);
                hl[rl * 128 + (col ^ ((rl & 7) << 2))] = v;
            }
        }
    }
    __syncthreads();

    // ---- GEMM2: h @ W2 (fp32 h, split hi+lo) ----
#pragma unroll
    for (int m = 0; m < 2; m++)
#pragma unroll
        for (int c = 0; c < 8; c++) acc[m][c] = (f32x4){0.f, 0.f, 0.f, 0.f};
#pragma unroll
    for (int kk = 0; kk < 4; kk++) {
        bf16x8 ah[2], al[2];
#pragma unroll
        for (int m = 0; m < 2; m++) {
            int rl = wid * 32 + m * 16 + r16;
            int sw = (rl & 7) << 2;
            int c0 = kk * 32 + kg * 8;
            float4 lo = *(const float4*)&hl[rl * 128 + (c0 ^ sw)];
            float4 hi = *(const float4*)&hl[rl * 128 + ((c0 + 4) ^ sw)];
            float v[8] = {lo.x, lo.y, lo.z, lo.w, hi.x, hi.y, hi.z, hi.w};
            bf16x8 th, tl;
#pragma unroll
            for (int j = 0; j < 8; j++) {
                short h = bfr(v[j]);
                th[j] = h;
                tl[j] = bfr(v[j] - bf2f(h));
            }
            ah[m] = th;
            al[m] = tl;
        }
#pragma unroll
        for (int c = 0; c < 8; c++) {
            bf16x8 wh = Wph2[kk * 512 + c * 64 + lane];
            bf16x8 wl = Wpl2[kk * 512 + c * 64 + lane];
#pragma unroll
            for (int m = 0; m < 2; m++) {
                acc[m][c] = __builtin_amdgcn_mfma_f32_16x16x32_bf16(ah[m], wh, acc[m][c], 0, 0, 0);
                acc[m][c] = __builtin_amdgcn_mfma_f32_16x16x32_bf16(al[m], wh, acc[m][c], 0, 0, 0);
                acc[m][c] = __builtin_amdgcn_mfma_f32_16x16x32_bf16(ah[m], wl, acc[m][c], 0, 0, 0);
            }
        }
    }
    // ---- epilogue2: relu(bn2) -> global bf16 ----
#pragma unroll
    for (int c = 0; c < 8; c++) {
        int col = c * 16 + r16;
        float s = sc2[col], o = bb2[col];
#pragma unroll
        for (int m = 0; m < 2; m++) {
            int rbase = row0 + m * 16 + kg * 4;
#pragma unroll
            for (int j = 0; j < 4; j++) {
                int row = rbase + j;
                if (row < NN)
                    Aout[(size_t)row * DD + col] =
                        (unsigned short)bfr(fmaxf(acc[m][c][j] * s + o, 0.f));
            }
        }
    }
}

// ---------------- pool (range-based, bf16 input) -> OUT[g][d] = max ----------------
__global__ void pool0_kernel(const unsigned short* __restrict__ X,
                             const int* __restrict__ gstart, float* __restrict__ OUT) {
    int gph = blockIdx.x;
    int d = threadIdx.x;  // 128
    int start = gstart[gph], end = gstart[gph + 1];
    float m;
    if (start >= end) {
        m = 0.f;
    } else {
        m = -INFINITY;
        for (int n = start; n < end; n++)
            m = fmaxf(m, bf2f((short)X[(size_t)n * DD + d]));
    }
    OUT[(size_t)gph * DD + d] = m;
}

// ------- fused pool + linear-accumulate (bf16 input): OUT[g] += pool @ W + b -------
__global__ __launch_bounds__(128) void poollin_kernel(const unsigned short* __restrict__ X,
                                                      const int* __restrict__ gstart,
                                                      const float* __restrict__ W,
                                                      const float* __restrict__ b,
                                                      float* __restrict__ OUT) {
    __shared__ float p[4][DD];
    int g0 = blockIdx.x * 4;
    int d = threadIdx.x;
#pragma unroll
    for (int gg = 0; gg < 4; gg++) {
        int start = gstart[g0 + gg], end = gstart[g0 + gg + 1];
        float m;
        if (start >= end) {
            m = 0.f;
        } else {
            m = -INFINITY;
            for (int n = start; n < end; n++)
                m = fmaxf(m, bf2f((short)X[(size_t)n * DD + d]));
        }
        p[gg][d] = m;
    }
    __syncthreads();
    float acc0 = b[d], acc1 = b[d], acc2 = b[d], acc3 = b[d];
#pragma unroll 8
    for (int k = 0; k < DD; k++) {
        float w = W[k * DD + d];
        acc0 += p[0][k] * w;
        acc1 += p[1][k] * w;
        acc2 += p[2][k] * w;
        acc3 += p[3][k] * w;
    }
    OUT[(size_t)(g0 + 0) * DD + d] += acc0;
    OUT[(size_t)(g0 + 1) * DD + d] += acc1;
    OUT[(size_t)(g0 + 2) * DD + d] += acc2;
    OUT[(size_t)(g0 + 3) * DD + d] += acc3;
}

// ---------------- post MLP -> scalar per graph ----------------
__global__ void post_kernel(const float* __restrict__ OUT, const float* __restrict__ W1,
                            const float* __restrict__ b1, const float* __restrict__ W2,
                            const float* __restrict__ b2, float* __restrict__ S) {
    __shared__ float o[DD];
    __shared__ float red[2];
    int gph = blockIdx.x, d = threadIdx.x;
    o[d] = fmaxf(OUT[(size_t)gph * DD + d], 0.f);
    __syncthreads();
    float acc = b1[d];
#pragma unroll 8
    for (int k = 0; k < DD; k++) acc += o[k] * W1[k * DD + d];
    acc = fmaxf(acc, 0.f);
    float v = acc * W2[d];
#pragma unroll
    for (int off = 32; off > 0; off >>= 1) v += __shfl_down(v, off);
    if ((d & 63) == 0) red[d >> 6] = v;
    __syncthreads();
    if (d == 0) S[gph] = red[0] + red[1] + b2[0];
}

// ---------------- decode ----------------
__global__ void pred_kernel(const int* __restrict__ eil, const int* __restrict__ el,
                            const float* __restrict__ S, float* __restrict__ out) {
    int i = blockIdx.x * blockDim.x + threadIdx.x;
    if (i >= NEL) return;
    int a = eil[i], b = eil[NEL + i];
    out[i] = S[a] * S[b];
    out[NEL + i] = (float)el[i];
}

extern "C" void kernel_launch(void* const* d_in, const int* in_sizes, int n_in,
                              void* d_out, int out_size, void* d_ws, size_t ws_size,
                              hipStream_t stream) {
    const float* x = (const float*)d_in[0];
    const int* edge_index = (const int*)d_in[1];
    const int* batch = (const int*)d_in[2];
    const int* eil = (const int*)d_in[3];
    const int* el = (const int*)d_in[4];
    const float* encW = (const float*)d_in[5];
    const float* encb = (const float*)d_in[6];
    const float* initW = (const float*)d_in[7];
    const float* initb = (const float*)d_in[8];
    const float* gin_eps = (const float*)d_in[9];
    const float* W1 = (const float*)d_in[10];
    const float* b1 = (const float*)d_in[11];
    const float* g1 = (const float*)d_in[12];
    const float* be1 = (const float*)d_in[13];
    const float* rm1 = (const float*)d_in[14];
    const float* rv1 = (const float*)d_in[15];
    const float* W2 = (const float*)d_in[16];
    const float* b2 = (const float*)d_in[17];
    const float* g2 = (const float*)d_in[18];
    const float* be2 = (const float*)d_in[19];
    const float* rm2 = (const float*)d_in[20];
    const float* rv2 = (const float*)d_in[21];
    const float* linW = (const float*)d_in[22];
    const float* linb = (const float*)d_in[23];
    const float* postW1 = (const float*)d_in[24];
    const float* postb1 = (const float*)d_in[25];
    const float* postW2 = (const float*)d_in[26];
    const float* postb2 = (const float*)d_in[27];

    const int* srcArr = edge_index;
    const int* dstArr = edge_index + NE;

    // workspace carve (256B aligned)
    char* w = (char*)d_ws;
    auto carve = [&](size_t bytes) -> char* {
        char* p = w;
        w += (bytes + 255) & ~(size_t)255;
        return p;
    };
    unsigned short* A = (unsigned short*)carve((size_t)NP * DD * 2);   // bf16 activations
    unsigned short* Bh = (unsigned short*)carve((size_t)NP * DD * 2);  // bf16 agg / init out
    float* OUTb = (float*)carve((size_t)NG * DD * 4);
    float* S = (float*)carve((size_t)NG * 4);
    int* deg = (int*)carve((size_t)NN * 4);
    int* rowptr = (int*)carve((size_t)(NN + 1) * 4);
    int* cursor = (int*)carve((size_t)NN * 4);
    int* csr_src = (int*)carve((size_t)NE * 4);
    int* bsum = (int*)carve((size_t)NB_SCAN * 4);
    int* boff = (int*)carve((size_t)NB_SCAN * 4);
    int* gstart = (int*)carve((size_t)(NG + 1) * 4);
    bf16x8* Wph = (bf16x8*)carve((size_t)9 * 2048 * 16);
    bf16x8* Wpl = (bf16x8*)carve((size_t)9 * 2048 * 16);
    float* scv = (float*)carve((size_t)9 * DD * 4);
    float* bbv = (float*)carve((size_t)9 * DD * 4);

    float* out = (float*)d_out;
    const int mmBlk = NP / 128;  // 1172

    // ---- prep (weights pack + BN fold) ----
    prep_w_kernel<<<72, 256, 0, stream>>>(initW, W1, W2, Wph, Wpl);
    prep_scb_kernel<<<5, 256, 0, stream>>>(initb, b1, g1, be1, rm1, rv1,
                                           b2, g2, be2, rm2, rv2, scv, bbv);

    // ---- CSR build (once, reused across 4 layers) ----
    zero_int_kernel<<<586, 256, 0, stream>>>(deg, NN);
    hist_kernel<<<2344, 256, 0, stream>>>(dstArr, deg);
    scan_reduce_kernel<<<NB_SCAN, 256, 0, stream>>>(deg, bsum);
    scan_mid_kernel<<<1, 256, 0, stream>>>(bsum, boff, rowptr + NN);
    scan_final_kernel<<<NB_SCAN, 256, 0, stream>>>(deg, boff, rowptr);
    copy_int_kernel<<<586, 256, 0, stream>>>(rowptr, cursor, NN);
    fill_kernel<<<2344, 256, 0, stream>>>(srcArr, dstArr, cursor, csr_src);
    gstart_kernel<<<586, 256, 0, stream>>>(batch, gstart);

    // ---- encoder -> A (bf16) ----
    enc_kernel<<<mmBlk, 256, 0, stream>>>(x, encW, encb, A);
    // Bh = bf16(A @ initW + initb)
    mm0_kernel<<<mmBlk, 256, 0, stream>>>(A, Bh, Wph, Wpl, scv, bbv);
    // OUT = pool(Bh)
    pool0_kernel<<<NG, DD, 0, stream>>>(Bh, gstart, OUTb);

    for (int i = 0; i < NL; i++) {
        // Bh = bf16( (1+eps)*A + CSR-sum(A) )   (one row per wave)
        agg_kernel<<<NN / 4, 256, 0, stream>>>(A, rowptr, csr_src, gin_eps, i, Bh);
        // A = bf16(relu(bn2( relu(bn1(Bh@W1)) @ W2 )))  — fused, h in LDS
        mm2x_kernel<<<mmBlk, 256, 0, stream>>>(
            Bh, A,
            Wph + (size_t)(1 + i) * 2048, Wpl + (size_t)(1 + i) * 2048,
            Wph + (size_t)(5 + i) * 2048, Wpl + (size_t)(5 + i) * 2048,
            scv + (1 + i) * DD, bbv + (1 + i) * DD,
            scv + (5 + i) * DD, bbv + (5 + i) * DD);
        // OUT += pool(A) @ linW + linb
        poollin_kernel<<<NG / 4, DD, 0, stream>>>(A, gstart, linW + (size_t)i * DD * DD,
                                                  linb + i * DD, OUTb);
    }

    post_kernel<<<NG, DD, 0, stream>>>(OUTb, postW1, postb1, postW2, postb2, S);
    pred_kernel<<<(NEL + 255) / 256, 256, 0, stream>>>(eil, el, S, out);
}